// Round 10
// baseline (155.596 us; speedup 1.0000x reference)
//
#include <hip/hip_runtime.h>
#include <hip/hip_bf16.h>
#include <cfloat>
#include <cstdint>
#include <cmath>

#define EMBED 768
#define NHEAD 12
#define SEQB  8
#define SEQ   512
#define HDIM  64
#define WMAT  589824  // 768*768

typedef __attribute__((ext_vector_type(8))) short short8;
typedef __attribute__((ext_vector_type(4))) short short4v;
typedef __attribute__((ext_vector_type(4))) float f32x4;

__device__ __forceinline__ short f2bf(float f) {
  uint32_t u = __float_as_uint(f);
  u += 0x7FFF + ((u >> 16) & 1u);
  return (short)(u >> 16);
}

// single-instruction bf16 round (RNE) via v_cvt_pk_bf16_f32
__device__ __forceinline__ short f2bf1(float f) {
  int r;
  asm("v_cvt_pk_bf16_f32 %0, %1, %2" : "=v"(r) : "v"(f), "v"(f));
  return (short)r;
}

__device__ __forceinline__ void gload_lds16(const void* g, void* l) {
  __builtin_amdgcn_global_load_lds((const __attribute__((address_space(1))) void*)g,
                                   (__attribute__((address_space(3))) void*)l, 16, 0, 0);
}

// ---------------- cast x to bf16 ----------------
__global__ void k_cast_x(const float* __restrict__ x, short* __restrict__ xb) {
  int i = blockIdx.x * blockDim.x + threadIdx.x;
  const int n4 = SEQB * SEQ * EMBED / 4;
  if (i < n4) {
    float4 v = ((const float4*)x)[i];
    short4v o;
    o.x = f2bf(v.x); o.y = f2bf(v.y); o.z = f2bf(v.z); o.w = f2bf(v.w);
    ((short4v*)xb)[i] = o;
  }
}

// ---------------- cast + transpose weights: Wt[mat][n][k] = W[mat][k][n] ----------------
__global__ void k_cast_wt(const float* __restrict__ Wq, const float* __restrict__ Wk,
                          const float* __restrict__ Wv, const float* __restrict__ Wo,
                          short* __restrict__ Wt) {
  __shared__ float tile[32][33];
  const int mat = blockIdx.z;
  const float* src = (mat == 0) ? Wq : (mat == 1) ? Wk : (mat == 2) ? Wv : Wo;
  const int n0 = blockIdx.x * 32, k0 = blockIdx.y * 32;
  const int tx = threadIdx.x & 31, ty = threadIdx.x >> 5;  // 32 x 8
  #pragma unroll
  for (int rr = 0; rr < 4; rr++)
    tile[ty + rr * 8][tx] = src[(size_t)(k0 + ty + rr * 8) * EMBED + n0 + tx];
  __syncthreads();
  short* dst = Wt + (size_t)mat * WMAT;
  #pragma unroll
  for (int rr = 0; rr < 4; rr++)
    dst[(size_t)(n0 + ty + rr * 8) * EMBED + k0 + tx] = f2bf(tile[tx][ty + rr * 8]);
}

// ---------------- GEMM: C[i][j] = sum_k A[i][k]*B[j][k], A:[I][768], B:[J][768] bf16 ----
// 2-phase pipelined: stage(s+1) issued before the wait for stage(s); counted vmcnt
// keeps the newest 4 loads in flight across both raw barriers (no full drain in loop).
// MODE 0 (QKV): i = n in [0,2304) (Wq^T|Wk^T|Wv^T rows), j = m=(b,s).
//               n<768 -> Q[B,H,S,D]; n<1536 -> K[B,H,S,D]; else -> Vt[B,H,D,S].
// MODE 2 (O):   i = n in [0,768) (Wo^T rows), j = m. fp32 out + bias.
template <int MODE>
__launch_bounds__(256)
__global__ void k_gemm(const short* __restrict__ A, const short* __restrict__ B,
                       short* __restrict__ O0, short* __restrict__ O1,
                       short* __restrict__ O2,
                       float* __restrict__ OF, const float* __restrict__ bias) {
  __shared__ __attribute__((aligned(16))) short As[2][128 * 32];
  __shared__ __attribute__((aligned(16))) short Bs[2][128 * 32];
  const int tid = threadIdx.x;
  const int lane = tid & 63, w = tid >> 6;
  const int g = lane >> 4, c = lane & 15;
  const int wi = (w >> 1) * 64, wj = (w & 1) * 64;
  const int i0 = blockIdx.y * 128, j0 = blockIdx.x * 128;
  const int NSTEP = EMBED / 32;  // 24

  f32x4 acc[4][4];
  #pragma unroll
  for (int a = 0; a < 4; a++)
    #pragma unroll
    for (int b2 = 0; b2 < 4; b2++) acc[a][b2] = (f32x4){0.f, 0.f, 0.f, 0.f};

  #define GSTAGE(S, BUF)                                                            \
    { _Pragma("unroll")                                                             \
      for (int it = 0; it < 2; it++) {                                              \
        int gi = tid + it * 256;                                                    \
        int row = gi >> 2, qq = gi & 3;                                             \
        gload_lds16(A + (size_t)(i0 + row) * EMBED + (S) * 32 + qq * 8,             \
                    &As[BUF][gi * 8]);                                              \
        gload_lds16(B + (size_t)(j0 + row) * EMBED + (S) * 32 + qq * 8,             \
                    &Bs[BUF][gi * 8]);                                              \
      } }

  GSTAGE(0, 0)
  __syncthreads();  // prologue full drain: tile 0 ready

  for (int s = 0; s < NSTEP; ++s) {
    const int cur = s & 1;
    if (s < NSTEP - 1) {
      GSTAGE(s + 1, cur ^ 1)
      asm volatile("s_waitcnt vmcnt(4)" ::: "memory");  // stage(s) landed; stage(s+1) in flight
    } else {
      asm volatile("s_waitcnt vmcnt(0)" ::: "memory");
    }
    __builtin_amdgcn_sched_barrier(0);
    __builtin_amdgcn_s_barrier();  // (b) tile s visible to all waves
    __builtin_amdgcn_sched_barrier(0);

    short8 aF[4], bF[4];
    #pragma unroll
    for (int mi = 0; mi < 4; mi++) aF[mi] = *(const short8*)&As[cur][(wi + mi * 16 + c) * 32 + g * 8];
    #pragma unroll
    for (int nj = 0; nj < 4; nj++) bF[nj] = *(const short8*)&Bs[cur][(wj + nj * 16 + c) * 32 + g * 8];
    #pragma unroll
    for (int mi = 0; mi < 4; mi++)
      #pragma unroll
      for (int nj = 0; nj < 4; nj++)
        acc[mi][nj] = __builtin_amdgcn_mfma_f32_16x16x32_bf16(aF[mi], bF[nj], acc[mi][nj], 0, 0, 0);

    __builtin_amdgcn_s_barrier();  // (a) all reads of tile s done -> buffer reusable
    __builtin_amdgcn_sched_barrier(0);
  }

  #pragma unroll
  for (int mi = 0; mi < 4; mi++) {
    int i = i0 + wi + mi * 16 + 4 * g;  // base of 4 consecutive i (the 4 acc regs)
    #pragma unroll
    for (int nj = 0; nj < 4; nj++) {
      int j = j0 + wj + nj * 16 + c;
      f32x4 v = acc[mi][nj];
      if (MODE == 0) {
        int n = i, m = j;
        int b = m >> 9, s = m & 511;
        if (n < 1536) {
          short* dst = O0; int nn = n;
          if (n >= 768) { dst = O1; nn -= 768; }
          int h = nn >> 6, d = nn & 63;
          short4v o; o.x = f2bf(v.x); o.y = f2bf(v.y); o.z = f2bf(v.z); o.w = f2bf(v.w);
          *(short4v*)&dst[(size_t)(((b * 12 + h) * 512 + s) * 64 + d)] = o;
        } else {
          int nn = n - 1536;
          int h = nn >> 6, d = nn & 63;
          size_t base = ((size_t)(b * 12 + h) * 64 + d) * 512 + s;
          O2[base] = f2bf(v.x); O2[base + 512] = f2bf(v.y);
          O2[base + 1024] = f2bf(v.z); O2[base + 1536] = f2bf(v.w);
        }
      } else {
        int n = i, m = j;
        float4 bb = *(const float4*)&bias[n];
        float4 o; o.x = v.x + bb.x; o.y = v.y + bb.y; o.z = v.z + bb.z; o.w = v.w + bb.w;
        *(float4*)&OF[(size_t)m * EMBED + n] = o;
      }
    }
  }
}

// ---------------- fused attention: per block (b, h, 64 q-rows) ----------------
// K/V tiles staged to LDS via global_load_lds, double-buffered, XOR-swizzled via
// pre-swizzled global source. 2-phase pipeline: counted vmcnt(2) + raw barriers,
// no full vmcnt drain in the loop.
__launch_bounds__(256)
__global__ void k_attn(const short* __restrict__ Q, const short* __restrict__ K,
                       const short* __restrict__ Vt, const int* __restrict__ mask,
                       const float* __restrict__ rel_pos, short* __restrict__ attO) {
  __shared__ float bias_lds[1024];
  __shared__ int mask_lds[512];
  __shared__ __attribute__((aligned(16))) short Plds[4][16 * 32];
  __shared__ __attribute__((aligned(16))) short Kbuf[2][32 * 64];  // [ktile rows][64 d]
  __shared__ __attribute__((aligned(16))) short Vbuf[2][64 * 32];  // [64 d][ktile]
  const int tid = threadIdx.x;
  const int lane = tid & 63, w = tid >> 6;
  const int g = lane >> 4, c = lane & 15;
  // XCD-affinity: all 8 q-blocks of one (b,h) land on the same XCD
  const int bid = blockIdx.x;
  const int q0 = (bid / 96) * 64;
  const int bh = bid % 96;
  const int b = bh / 12, h = bh % 12;
  const short* Qb = Q + (size_t)bh * (512 * 64);
  const short* Kb = K + (size_t)bh * (512 * 64);
  const short* Vb = Vt + (size_t)bh * (64 * 512);

  const float LOG2E = 1.44269504089f;
  for (int i = tid; i < 1023; i += 256) bias_lds[i] = (rel_pos[i * 12 + h] - 16.0f) * LOG2E;
  for (int i = tid; i < 512; i += 256) mask_lds[i] = mask[b * 512 + i];

  // stage granule indices (per thread, fixed):
  //   K tile: 32 rows x 8 chunks of 16B; source chunk pre-swizzled by row&7
  //   V tile: 64 rows x 4 chunks of 16B; source chunk pre-swizzled by (row>>1)&3
  const int krow_s = tid >> 3, kc_s = tid & 7;
  const int vrow_s = tid >> 2, vc_s = tid & 3;
  #define STAGEKV(T, BUF)                                                             \
    {                                                                                 \
      gload_lds16(Kb + ((T) * 32 + krow_s) * 64 + (kc_s ^ (krow_s & 7)) * 8,          \
                  &Kbuf[BUF][tid * 8]);                                               \
      gload_lds16(Vb + (size_t)vrow_s * 512 + (T) * 32 + (vc_s ^ ((vrow_s >> 1) & 3)) * 8, \
                  &Vbuf[BUF][tid * 8]);                                               \
    }

  STAGEKV(0, 0)

  short8 qf[2];
  #pragma unroll
  for (int dc = 0; dc < 2; dc++)
    qf[dc] = *(const short8*)&Qb[(q0 + w * 16 + c) * 64 + dc * 32 + g * 8];

  __syncthreads();  // prologue full drain: bias/mask + tile 0 ready

  int qrow[4], mq[4], bbase[4];
  #pragma unroll
  for (int r = 0; r < 4; r++) {
    qrow[r] = q0 + w * 16 + 4 * g + r;
    mq[r] = mask_lds[qrow[r]];
    bbase[r] = 511 - qrow[r];
  }

  float l_part[4];
  f32x4 accO[4];
  #pragma unroll
  for (int r = 0; r < 4; r++) l_part[r] = 0.f;
  #pragma unroll
  for (int dt = 0; dt < 4; dt++) accO[dt] = (f32x4){0.f, 0.f, 0.f, 0.f};

  const float SC = 0.125f * 1.44269504089f;
  short* Pw = &Plds[w][0];
  const int rdoff = c * 32 + g * 8;
  // swizzled LDS read offsets (element units)
  const int kswz = c & 7;          // K chunk XOR
  const int vswz = (c >> 1) & 3;   // V chunk XOR

  for (int t = 0; t < 16; ++t) {
    const int cur = t & 1;
    if (t < 15) {
      STAGEKV(t + 1, cur ^ 1)
      asm volatile("s_waitcnt vmcnt(2)" ::: "memory");  // stage(t) landed; stage(t+1) in flight
    } else {
      asm volatile("s_waitcnt vmcnt(0)" ::: "memory");
    }
    __builtin_amdgcn_sched_barrier(0);
    __builtin_amdgcn_s_barrier();  // (b) tile t visible to all waves
    __builtin_amdgcn_sched_barrier(0);

    const short* Kt = &Kbuf[cur][0];
    const short* Vs = &Vbuf[cur][0];

    short8 kf[4], vf[4];
    #pragma unroll
    for (int ct = 0; ct < 2; ct++)
      #pragma unroll
      for (int dc = 0; dc < 2; dc++)
        kf[ct * 2 + dc] = *(const short8*)&Kt[(ct * 16 + c) * 64 + ((dc * 4 + g) ^ kswz) * 8];
    #pragma unroll
    for (int dt = 0; dt < 4; dt++)
      vf[dt] = *(const short8*)&Vs[(dt * 16 + c) * 32 + ((g ^ vswz)) * 8];

    f32x4 s0 = (f32x4){0.f, 0.f, 0.f, 0.f}, s1 = s0;
    s0 = __builtin_amdgcn_mfma_f32_16x16x32_bf16(qf[0], kf[0], s0, 0, 0, 0);
    s0 = __builtin_amdgcn_mfma_f32_16x16x32_bf16(qf[1], kf[1], s0, 0, 0, 0);
    s1 = __builtin_amdgcn_mfma_f32_16x16x32_bf16(qf[0], kf[2], s1, 0, 0, 0);
    s1 = __builtin_amdgcn_mfma_f32_16x16x32_bf16(qf[1], kf[3], s1, 0, 0, 0);

    float p_[2][4];
    {
      const int krow = t * 32 + c;
      const int mk0 = mask_lds[krow], mk1 = mask_lds[krow + 16];
      #pragma unroll
      for (int r = 0; r < 4; r++) {
        float a0 = fmaf(s0[r], SC, bias_lds[krow + bbase[r]]);
        float a1 = fmaf(s1[r], SC, bias_lds[krow + 16 + bbase[r]]);
        float p0 = exp2f(a0), p1 = exp2f(a1);
        if ((mq[r] & mk0) == 0) p0 = 0.f;
        if ((mq[r] & mk1) == 0) p1 = 0.f;
        p_[0][r] = p0; p_[1][r] = p1;
        l_part[r] += p0 + p1;
      }
    }
    #pragma unroll
    for (int ct = 0; ct < 2; ct++)
      #pragma unroll
      for (int r = 0; r < 4; r++)
        Pw[(4 * g + r) * 32 + ct * 16 + c] = f2bf1(p_[ct][r]);
    short8 pa = *(const short8*)&Pw[rdoff];
    #pragma unroll
    for (int dt = 0; dt < 4; dt++)
      accO[dt] = __builtin_amdgcn_mfma_f32_16x16x32_bf16(pa, vf[dt], accO[dt], 0, 0, 0);

    __builtin_amdgcn_s_barrier();  // (a) all reads of tile t done -> buffer reusable
    __builtin_amdgcn_sched_barrier(0);
  }

  float inv[4];
  #pragma unroll
  for (int r = 0; r < 4; r++) {
    float lr = l_part[r];
    #pragma unroll
    for (int off = 1; off < 16; off <<= 1) lr += __shfl_xor(lr, off);
    inv[r] = 1.0f / lr;
  }
  #pragma unroll
  for (int dt = 0; dt < 4; dt++)
    #pragma unroll
    for (int r = 0; r < 4; r++)
      attO[(size_t)(b * 512 + qrow[r]) * EMBED + h * 64 + dt * 16 + c] =
          f2bf(accO[dt][r] * inv[r]);
}

extern "C" void kernel_launch(void* const* d_in, const int* in_sizes, int n_in,
                              void* d_out, int out_size, void* d_ws, size_t ws_size,
                              hipStream_t stream) {
  const float* x = (const float*)d_in[0];
  const int* mask = (const int*)d_in[1];
  const float* Wq = (const float*)d_in[2];
  const float* Wk = (const float*)d_in[3];
  const float* Wv = (const float*)d_in[4];
  const float* rel_pos = (const float*)d_in[5];
  const float* Wo = (const float*)d_in[6];
  const float* bo = (const float*)d_in[7];
  float* out = (float*)d_out;

  char* ws = (char*)d_ws;
  short* xb = (short*)ws;                                    // 4096*768 bf16 = 6291456 B
  short* Wt = (short*)(ws + 6291456);                        // 4*768*768 bf16 = 4718592 B
  short* Qg = (short*)(ws + 6291456 + 4718592);              // [B,H,S,D] bf16
  short* Kg = Qg + 3145728;                                  // [B,H,S,D]
  short* Vt = Kg + 3145728;                                  // [B,H,D,S]
  short* attO = xb;                                          // alias: xb dead after QKV-GEMM

  k_cast_x<<<3072, 256, 0, stream>>>(x, xb);
  k_cast_wt<<<dim3(24, 24, 4), 256, 0, stream>>>(Wq, Wk, Wv, Wo, Wt);
  // QKV fused: A = Wt_q|Wt_k|Wt_v rows (i=2304), B = xb (j=4096)
  k_gemm<0><<<dim3(32, 18), 256, 0, stream>>>(Wt, xb, Qg, Kg, Vt, nullptr, nullptr);
  // attention (1D grid, XCD-affinity remap inside)
  k_attn<<<768, 256, 0, stream>>>(Qg, Kg, Vt, mask, rel_pos, attO);
  // O: A = Wt_o rows (i=768), B = attO (j=4096), fp32 out + bias
  k_gemm<2><<<dim3(32, 6), 256, 0, stream>>>(Wt + 3 * WMAT, attO, nullptr, nullptr, nullptr, out, bo);
}

// Round 11
// 149.506 us; speedup vs baseline: 1.0407x; 1.0407x over previous
//
#include <hip/hip_runtime.h>
#include <hip/hip_bf16.h>
#include <cfloat>
#include <cstdint>
#include <cmath>

#define EMBED 768
#define NHEAD 12
#define SEQB  8
#define SEQ   512
#define HDIM  64
#define WMAT  589824  // 768*768

typedef __attribute__((ext_vector_type(8))) short short8;
typedef __attribute__((ext_vector_type(4))) short short4v;
typedef __attribute__((ext_vector_type(4))) float f32x4;

__device__ __forceinline__ short f2bf(float f) {
  uint32_t u = __float_as_uint(f);
  u += 0x7FFF + ((u >> 16) & 1u);
  return (short)(u >> 16);
}

// single-instruction bf16 round (RNE) via v_cvt_pk_bf16_f32
__device__ __forceinline__ short f2bf1(float f) {
  int r;
  asm("v_cvt_pk_bf16_f32 %0, %1, %2" : "=v"(r) : "v"(f), "v"(f));
  return (short)r;
}

__device__ __forceinline__ void gload_lds16(const void* g, void* l) {
  __builtin_amdgcn_global_load_lds((const __attribute__((address_space(1))) void*)g,
                                   (__attribute__((address_space(3))) void*)l, 16, 0, 0);
}

// ---------------- fused casts: blocks [0,2304) transpose+cast weights; rest cast x ----
__global__ void k_cast(const float* __restrict__ x,
                       const float* __restrict__ Wq, const float* __restrict__ Wk,
                       const float* __restrict__ Wv, const float* __restrict__ Wo,
                       short* __restrict__ xb, short* __restrict__ Wt) {
  __shared__ float tile[32][33];
  const int bx = blockIdx.x;
  if (bx < 2304) {
    const int mat = bx / 576, rem = bx % 576;
    const float* src = (mat == 0) ? Wq : (mat == 1) ? Wk : (mat == 2) ? Wv : Wo;
    const int n0 = (rem % 24) * 32, k0 = (rem / 24) * 32;
    const int tx = threadIdx.x & 31, ty = threadIdx.x >> 5;  // 32 x 8
    #pragma unroll
    for (int rr = 0; rr < 4; rr++)
      tile[ty + rr * 8][tx] = src[(size_t)(k0 + ty + rr * 8) * EMBED + n0 + tx];
    __syncthreads();
    short* dst = Wt + (size_t)mat * WMAT;
    #pragma unroll
    for (int rr = 0; rr < 4; rr++)
      dst[(size_t)(n0 + ty + rr * 8) * EMBED + k0 + tx] = f2bf(tile[tx][ty + rr * 8]);
  } else {
    int i = (bx - 2304) * 256 + threadIdx.x;  // exactly 3072 blocks cover n4
    float4 v = ((const float4*)x)[i];
    short4v o;
    o.x = f2bf(v.x); o.y = f2bf(v.y); o.z = f2bf(v.z); o.w = f2bf(v.w);
    ((short4v*)xb)[i] = o;
  }
}

// ---------------- GEMM: C[i][j] = sum_k A[i][k]*B[j][k], A:[I][768], B:[J][768] bf16 ----
// 2-deep pipelined (3 LDS buffers): stage(s+2) issued before the wait for stage(s);
// vmcnt(8) keeps the 8 newest loads (tiles s+1, s+2) in flight across barriers.
// MODE 0 (QKV): i = n in [0,2304) (Wq^T|Wk^T|Wv^T rows), j = m=(b,s).
//               n<768 -> Q[B,H,S,D]; n<1536 -> K[B,H,S,D]; else -> Vt[B,H,D,S].
// MODE 2 (O):   i = n in [0,768) (Wo^T rows), j = m. fp32 out + bias.
template <int MODE>
__launch_bounds__(256)
__global__ void k_gemm(const short* __restrict__ A, const short* __restrict__ B,
                       short* __restrict__ O0, short* __restrict__ O1,
                       short* __restrict__ O2,
                       float* __restrict__ OF, const float* __restrict__ bias) {
  __shared__ __attribute__((aligned(16))) short As[3][128 * 32];
  __shared__ __attribute__((aligned(16))) short Bs[3][128 * 32];
  const int tid = threadIdx.x;
  const int lane = tid & 63, w = tid >> 6;
  const int g = lane >> 4, c = lane & 15;
  const int wi = (w >> 1) * 64, wj = (w & 1) * 64;
  const int i0 = blockIdx.y * 128, j0 = blockIdx.x * 128;
  const int NSTEP = EMBED / 32;  // 24

  f32x4 acc[4][4];
  #pragma unroll
  for (int a = 0; a < 4; a++)
    #pragma unroll
    for (int b2 = 0; b2 < 4; b2++) acc[a][b2] = (f32x4){0.f, 0.f, 0.f, 0.f};

  #define GSTAGE(S, BUF)                                                            \
    { _Pragma("unroll")                                                             \
      for (int it = 0; it < 2; it++) {                                              \
        int gi = tid + it * 256;                                                    \
        int row = gi >> 2, qq = gi & 3;                                             \
        gload_lds16(A + (size_t)(i0 + row) * EMBED + (S) * 32 + qq * 8,             \
                    &As[BUF][gi * 8]);                                              \
        gload_lds16(B + (size_t)(j0 + row) * EMBED + (S) * 32 + qq * 8,             \
                    &Bs[BUF][gi * 8]);                                              \
      } }

  GSTAGE(0, 0)
  GSTAGE(1, 1)

  for (int s = 0; s < NSTEP; ++s) {
    const int cur = s % 3;
    if (s + 2 < NSTEP) {
      GSTAGE(s + 2, (s + 2) % 3)
      asm volatile("s_waitcnt vmcnt(8)" ::: "memory");  // tile s landed; s+1,s+2 in flight
    } else if (s + 1 < NSTEP) {
      asm volatile("s_waitcnt vmcnt(4)" ::: "memory");  // tile s landed; s+1 in flight
    } else {
      asm volatile("s_waitcnt vmcnt(0)" ::: "memory");
    }
    __builtin_amdgcn_sched_barrier(0);
    __builtin_amdgcn_s_barrier();  // (b) tile s visible to all waves
    __builtin_amdgcn_sched_barrier(0);

    short8 aF[4], bF[4];
    #pragma unroll
    for (int mi = 0; mi < 4; mi++) aF[mi] = *(const short8*)&As[cur][(wi + mi * 16 + c) * 32 + g * 8];
    #pragma unroll
    for (int nj = 0; nj < 4; nj++) bF[nj] = *(const short8*)&Bs[cur][(wj + nj * 16 + c) * 32 + g * 8];
    #pragma unroll
    for (int mi = 0; mi < 4; mi++)
      #pragma unroll
      for (int nj = 0; nj < 4; nj++)
        acc[mi][nj] = __builtin_amdgcn_mfma_f32_16x16x32_bf16(aF[mi], bF[nj], acc[mi][nj], 0, 0, 0);

    __builtin_amdgcn_s_barrier();  // (a) all reads of tile s done -> its buffer reusable
    __builtin_amdgcn_sched_barrier(0);
  }

  #pragma unroll
  for (int mi = 0; mi < 4; mi++) {
    int i = i0 + wi + mi * 16 + 4 * g;  // base of 4 consecutive i (the 4 acc regs)
    #pragma unroll
    for (int nj = 0; nj < 4; nj++) {
      int j = j0 + wj + nj * 16 + c;
      f32x4 v = acc[mi][nj];
      if (MODE == 0) {
        int n = i, m = j;
        int b = m >> 9, s = m & 511;
        if (n < 1536) {
          short* dst = O0; int nn = n;
          if (n >= 768) { dst = O1; nn -= 768; }
          int h = nn >> 6, d = nn & 63;
          short4v o; o.x = f2bf(v.x); o.y = f2bf(v.y); o.z = f2bf(v.z); o.w = f2bf(v.w);
          *(short4v*)&dst[(size_t)(((b * 12 + h) * 512 + s) * 64 + d)] = o;
        } else {
          int nn = n - 1536;
          int h = nn >> 6, d = nn & 63;
          size_t base = ((size_t)(b * 12 + h) * 64 + d) * 512 + s;
          O2[base] = f2bf(v.x); O2[base + 512] = f2bf(v.y);
          O2[base + 1024] = f2bf(v.z); O2[base + 1536] = f2bf(v.w);
        }
      } else {
        int n = i, m = j;
        float4 bb = *(const float4*)&bias[n];
        float4 o; o.x = v.x + bb.x; o.y = v.y + bb.y; o.z = v.z + bb.z; o.w = v.w + bb.w;
        *(float4*)&OF[(size_t)m * EMBED + n] = o;
      }
    }
  }
}

// ---------------- fused attention: per block (b, h, 64 q-rows), KVBLK=64 ----------------
// K/V 64-row tiles staged to LDS via global_load_lds, double-buffered; unified XOR
// swizzle chunk^=(row&7) applied on the global source (linear LDS dest) and mirrored
// on the ds_read side. 8 iterations, counted vmcnt(4), raw barriers.
__launch_bounds__(256)
__global__ void k_attn(const short* __restrict__ Q, const short* __restrict__ K,
                       const short* __restrict__ Vt, const int* __restrict__ mask,
                       const float* __restrict__ rel_pos, short* __restrict__ attO) {
  __shared__ float bias_lds[1024];
  __shared__ int mask_lds[512];
  __shared__ __attribute__((aligned(16))) short Plds[4][16 * 64];
  __shared__ __attribute__((aligned(16))) short Kbuf[2][64 * 64];  // [k-row][64 d]
  __shared__ __attribute__((aligned(16))) short Vbuf[2][64 * 64];  // [64 d][64 k]
  const int tid = threadIdx.x;
  const int lane = tid & 63, w = tid >> 6;
  const int g = lane >> 4, c = lane & 15;
  // XCD-affinity: all 8 q-blocks of one (b,h) land on the same XCD
  const int bid = blockIdx.x;
  const int q0 = (bid / 96) * 64;
  const int bh = bid % 96;
  const int b = bh / 12, h = bh % 12;
  const short* Qb = Q + (size_t)bh * (512 * 64);
  const short* Kb = K + (size_t)bh * (512 * 64);
  const short* Vb = Vt + (size_t)bh * (64 * 512);

  const float LOG2E = 1.44269504089f;
  for (int i = tid; i < 1023; i += 256) bias_lds[i] = (rel_pos[i * 12 + h] - 16.0f) * LOG2E;
  for (int i = tid; i < 512; i += 256) mask_lds[i] = mask[b * 512 + i];

  // staging: K tile 64 rows x 8 chunks of 16B; V tile 64 d-rows x 8 chunks of 16B.
  // 2 granules each per thread (gi = tid, tid+256). Source chunk pre-swizzled by row&7.
  #define STAGEKV(T, BUF)                                                             \
    { _Pragma("unroll")                                                               \
      for (int it = 0; it < 2; it++) {                                                \
        int gi = tid + it * 256;                                                      \
        int row = gi >> 3, ch = gi & 7;                                               \
        gload_lds16(Kb + ((T) * 64 + row) * 64 + (ch ^ (row & 7)) * 8,                \
                    &Kbuf[BUF][gi * 8]);                                              \
        gload_lds16(Vb + (size_t)row * 512 + (T) * 64 + (ch ^ (row & 7)) * 8,         \
                    &Vbuf[BUF][gi * 8]);                                              \
      } }

  STAGEKV(0, 0)

  short8 qf[2];
  #pragma unroll
  for (int dc = 0; dc < 2; dc++)
    qf[dc] = *(const short8*)&Qb[(q0 + w * 16 + c) * 64 + dc * 32 + g * 8];

  __syncthreads();  // prologue full drain: bias/mask + tile 0 ready

  int qrow[4], mq[4], bbase[4];
  #pragma unroll
  for (int r = 0; r < 4; r++) {
    qrow[r] = q0 + w * 16 + 4 * g + r;
    mq[r] = mask_lds[qrow[r]];
    bbase[r] = 511 - qrow[r];
  }

  float l_part[4];
  f32x4 accO[4];
  #pragma unroll
  for (int r = 0; r < 4; r++) l_part[r] = 0.f;
  #pragma unroll
  for (int dt = 0; dt < 4; dt++) accO[dt] = (f32x4){0.f, 0.f, 0.f, 0.f};

  const float SC = 0.125f * 1.44269504089f;
  short* Pw = &Plds[w][0];
  const int cswz = c & 7;  // chunk XOR for both K and V reads (row === c mod 16)

  for (int t = 0; t < 8; ++t) {
    const int cur = t & 1;
    if (t < 7) {
      STAGEKV(t + 1, cur ^ 1)
      asm volatile("s_waitcnt vmcnt(4)" ::: "memory");  // tile t landed; t+1 in flight
    } else {
      asm volatile("s_waitcnt vmcnt(0)" ::: "memory");
    }
    __builtin_amdgcn_sched_barrier(0);
    __builtin_amdgcn_s_barrier();  // (b) tile t visible
    __builtin_amdgcn_sched_barrier(0);

    const short* Kt = &Kbuf[cur][0];
    const short* Vs = &Vbuf[cur][0];

    // QK^T for 4 ct-tiles of 16 k-rows
    f32x4 s4[4];
    #pragma unroll
    for (int ct = 0; ct < 4; ct++) {
      short8 kf0 = *(const short8*)&Kt[(ct * 16 + c) * 64 + ((0 + g) ^ cswz) * 8];
      short8 kf1 = *(const short8*)&Kt[(ct * 16 + c) * 64 + ((4 + g) ^ cswz) * 8];
      f32x4 s = (f32x4){0.f, 0.f, 0.f, 0.f};
      s = __builtin_amdgcn_mfma_f32_16x16x32_bf16(qf[0], kf0, s, 0, 0, 0);
      s = __builtin_amdgcn_mfma_f32_16x16x32_bf16(qf[1], kf1, s, 0, 0, 0);
      s4[ct] = s;
    }

    // softmax (fixed-offset, exp2 domain) + P pack to LDS
    #pragma unroll
    for (int ct = 0; ct < 4; ct++) {
      const int krow = t * 64 + ct * 16 + c;
      const int mk = mask_lds[krow];
      float p_[4];
      #pragma unroll
      for (int r = 0; r < 4; r++) {
        float a0 = fmaf(s4[ct][r], SC, bias_lds[krow + bbase[r]]);
        float pv = exp2f(a0);
        if ((mq[r] & mk) == 0) pv = 0.f;
        p_[r] = pv;
        l_part[r] += pv;
      }
      #pragma unroll
      for (int r = 0; r < 4; r++)
        Pw[(4 * g + r) * 64 + ct * 16 + c] = f2bf1(p_[r]);
    }

    // PV: two 32-k subtiles
    short8 pa0 = *(const short8*)&Pw[c * 64 + g * 8];
    short8 pa1 = *(const short8*)&Pw[c * 64 + 32 + g * 8];
    #pragma unroll
    for (int dt = 0; dt < 4; dt++) {
      short8 vf0 = *(const short8*)&Vs[(dt * 16 + c) * 64 + ((0 + g) ^ cswz) * 8];
      short8 vf1 = *(const short8*)&Vs[(dt * 16 + c) * 64 + ((4 + g) ^ cswz) * 8];
      accO[dt] = __builtin_amdgcn_mfma_f32_16x16x32_bf16(pa0, vf0, accO[dt], 0, 0, 0);
      accO[dt] = __builtin_amdgcn_mfma_f32_16x16x32_bf16(pa1, vf1, accO[dt], 0, 0, 0);
    }

    __builtin_amdgcn_s_barrier();  // (a) reads of tile t done -> buffer reusable
    __builtin_amdgcn_sched_barrier(0);
  }

  float inv[4];
  #pragma unroll
  for (int r = 0; r < 4; r++) {
    float lr = l_part[r];
    #pragma unroll
    for (int off = 1; off < 16; off <<= 1) lr += __shfl_xor(lr, off);
    inv[r] = 1.0f / lr;
  }
  #pragma unroll
  for (int dt = 0; dt < 4; dt++)
    #pragma unroll
    for (int r = 0; r < 4; r++)
      attO[(size_t)(b * 512 + qrow[r]) * EMBED + h * 64 + dt * 16 + c] =
          f2bf(accO[dt][r] * inv[r]);
}

extern "C" void kernel_launch(void* const* d_in, const int* in_sizes, int n_in,
                              void* d_out, int out_size, void* d_ws, size_t ws_size,
                              hipStream_t stream) {
  const float* x = (const float*)d_in[0];
  const int* mask = (const int*)d_in[1];
  const float* Wq = (const float*)d_in[2];
  const float* Wk = (const float*)d_in[3];
  const float* Wv = (const float*)d_in[4];
  const float* rel_pos = (const float*)d_in[5];
  const float* Wo = (const float*)d_in[6];
  const float* bo = (const float*)d_in[7];
  float* out = (float*)d_out;

  char* ws = (char*)d_ws;
  short* xb = (short*)ws;                                    // 4096*768 bf16 = 6291456 B
  short* Wt = (short*)(ws + 6291456);                        // 4*768*768 bf16 = 4718592 B
  short* Qg = (short*)(ws + 6291456 + 4718592);              // [B,H,S,D] bf16
  short* Kg = Qg + 3145728;                                  // [B,H,S,D]
  short* Vt = Kg + 3145728;                                  // [B,H,D,S]
  short* attO = xb;                                          // alias: xb dead after QKV-GEMM

  // fused casts: 2304 weight-transpose blocks + 3072 x-cast blocks
  k_cast<<<5376, 256, 0, stream>>>(x, Wq, Wk, Wv, Wo, xb, Wt);
  // QKV fused: A = Wt_q|Wt_k|Wt_v rows (i=2304), B = xb (j=4096)
  k_gemm<0><<<dim3(32, 18), 256, 0, stream>>>(Wt, xb, Qg, Kg, Vt, nullptr, nullptr);
  // attention (1D grid, XCD-affinity remap inside)
  k_attn<<<768, 256, 0, stream>>>(Qg, Kg, Vt, mask, rel_pos, attO);
  // O: A = Wt_o rows (i=768), B = attO (j=4096), fp32 out + bias
  k_gemm<2><<<dim3(32, 6), 256, 0, stream>>>(Wt + 3 * WMAT, attO, nullptr, nullptr, nullptr, out, bo);
}